// Round 4
// baseline (660.148 us; speedup 1.0000x reference)
//
#include <hip/hip_runtime.h>
#include <hip/hip_cooperative_groups.h>
#include <math.h>

#define BATCH 4
#define SEQ   4096
#define DIM   1024
#define VEC   4

// Cooperative single-kernel: NCC chunks of SC rows per batch chain.
#define NCC 256
#define SC  (SEQ / NCC)   // 16

// Fallback 2-kernel path: NC2 chunks of S2 rows.
#define NC2 128
#define S2  (SEQ / NC2)   // 32

typedef float f32x4 __attribute__((ext_vector_type(4)));

namespace cg = cooperative_groups;

// Per-d parameters: a = phazor = p/|p| * exp(-|p|), b = phazor_init.
__device__ __forceinline__ void load_params4(
    const float* __restrict__ phr, const float* __restrict__ phi,
    const float* __restrict__ pir, const float* __restrict__ pii,
    int d0, float* ar, float* ai, float* br, float* bi)
{
    float4 p_r = *reinterpret_cast<const float4*>(phr + d0);
    float4 p_i = *reinterpret_cast<const float4*>(phi + d0);
    float4 q_r = *reinterpret_cast<const float4*>(pir + d0);
    float4 q_i = *reinterpret_cast<const float4*>(pii + d0);
    float prv[VEC] = {p_r.x, p_r.y, p_r.z, p_r.w};
    float piv[VEC] = {p_i.x, p_i.y, p_i.z, p_i.w};
    float qrv[VEC] = {q_r.x, q_r.y, q_r.z, q_r.w};
    float qiv[VEC] = {q_i.x, q_i.y, q_i.z, q_i.w};
#pragma unroll
    for (int j = 0; j < VEC; ++j) {
        float mag = sqrtf(prv[j] * prv[j] + piv[j] * piv[j]);
        float s = expf(-mag) / mag;
        ar[j] = prv[j] * s;
        ai[j] = piv[j] * s;
        br[j] = qrv[j];
        bi[j] = qiv[j];
    }
}

// ---------------- cooperative single-kernel path ----------------
// Grid = BATCH*NCC = 1024 blocks of 256 threads; launch_bounds(256,4) forces
// VGPR<=128 so 4 blocks/CU * 256 CUs = 1024 co-resident (structural guarantee
// for the cooperative launch). x chunk is held in registers across both syncs
// so HBM reads x exactly once.
template <bool CPLX>
__global__ __launch_bounds__(256, 4) void k_coop(
    const float* __restrict__ x,
    const float* __restrict__ phr, const float* __restrict__ phi,
    const float* __restrict__ pir, const float* __restrict__ pii,
    const float* __restrict__ hr,  const float* __restrict__ hi_,
    float2* __restrict__ carry, float2* __restrict__ prefix,
    float* __restrict__ out)
{
    const int tid = threadIdx.x;
    const int d0  = tid * VEC;
    const int c   = blockIdx.x % NCC;
    const int b   = blockIdx.x / NCC;

    float ar[VEC], ai[VEC], bqr[VEC], bqi[VEC];
    load_params4(phr, phi, pir, pii, d0, ar, ai, bqr, bqi);

    // ---- Phase 1: load x chunk to regs, local scan (zero seed), write carry.
    float xr[SC][VEC];
    const float* xp = x + ((size_t)b * SEQ + (size_t)c * SC) * DIM + d0;
#pragma unroll
    for (int t = 0; t < SC; ++t) {
        float4 v = *reinterpret_cast<const float4*>(xp + (size_t)t * DIM);
        xr[t][0] = v.x; xr[t][1] = v.y; xr[t][2] = v.z; xr[t][3] = v.w;
    }
    {
        float Cr[VEC] = {0.f, 0.f, 0.f, 0.f}, Ci[VEC] = {0.f, 0.f, 0.f, 0.f};
#pragma unroll
        for (int t = 0; t < SC; ++t)
#pragma unroll
            for (int j = 0; j < VEC; ++j) {
                float nr = fmaf(ar[j], Cr[j], fmaf(-ai[j], Ci[j], bqr[j] * xr[t][j]));
                float ni = fmaf(ar[j], Ci[j], fmaf( ai[j], Cr[j], bqi[j] * xr[t][j]));
                Cr[j] = nr; Ci[j] = ni;
            }
        f32x4* cp = reinterpret_cast<f32x4*>(carry + ((size_t)b * NCC + c) * DIM + d0);
        cp[0] = f32x4{Cr[0], Ci[0], Cr[1], Ci[1]};   // regular (cached) stores:
        cp[1] = f32x4{Cr[2], Ci[2], Cr[3], Ci[3]};   // phase 2 re-reads these
    }

    __threadfence();
    cg::this_grid().sync();

    // ---- Phase 2: 16 worker blocks spread across the grid (different CUs/XCDs)
    // compute the exact per-(b,d) prefix scan over NCC carries.
    if ((blockIdx.x & 63) == 0) {
        const int gt = (blockIdx.x >> 6) * 256 + tid;   // 0..4095 = b*DIM+d
        const int pb = gt >> 10, pd = gt & (DIM - 1);
        float pr = phr[pd], pi = phi[pd];
        float mag = sqrtf(pr * pr + pi * pi);
        float s = expf(-mag) / mag;
        float a1r = pr * s, a1i = pi * s;
        // AS = a^SC (SC=16 -> 4 squarings)
        float ASr = a1r, ASi = a1i;
#pragma unroll
        for (int k = 0; k < 4; ++k) {
            float nr = ASr * ASr - ASi * ASi;
            ASi = 2.f * ASr * ASi;
            ASr = nr;
        }
        float Pr = hr[gt], Pi = hi_[gt];
        const float2* cb = carry  + (size_t)pb * NCC * DIM + pd;
        float2*       pp = prefix + (size_t)pb * NCC * DIM + pd;
#pragma unroll 4
        for (int k = 0; k < NCC; ++k) {
            pp[(size_t)k * DIM] = make_float2(Pr, Pi);
            float2 cv = cb[(size_t)k * DIM];
            float nr = fmaf(ASr, Pr, fmaf(-ASi, Pi, cv.x));
            float ni = fmaf(ASr, Pi, fmaf( ASi, Pr, cv.y));
            Pr = nr; Pi = ni;
        }
    }

    __threadfence();
    cg::this_grid().sync();

    // ---- Phase 3: seed from prefix, replay scan from regs, NT-store out.
    float Cr[VEC], Ci[VEC];
    {
        const f32x4* sp =
            reinterpret_cast<const f32x4*>(prefix + ((size_t)b * NCC + c) * DIM + d0);
        f32x4 s0 = sp[0], s1 = sp[1];
        Cr[0] = s0.x; Ci[0] = s0.y; Cr[1] = s0.z; Ci[1] = s0.w;
        Cr[2] = s1.x; Ci[2] = s1.y; Cr[3] = s1.z; Ci[3] = s1.w;
    }
    const size_t obase = ((size_t)b * SEQ + (size_t)c * SC) * DIM + d0;
#pragma unroll
    for (int t = 0; t < SC; ++t) {
#pragma unroll
        for (int j = 0; j < VEC; ++j) {
            float nr = fmaf(ar[j], Cr[j], fmaf(-ai[j], Ci[j], bqr[j] * xr[t][j]));
            float ni = fmaf(ar[j], Ci[j], fmaf( ai[j], Cr[j], bqi[j] * xr[t][j]));
            Cr[j] = nr; Ci[j] = ni;
        }
        if (CPLX) {
            f32x4* dst = reinterpret_cast<f32x4*>(out + 2 * (obase + (size_t)t * DIM));
            __builtin_nontemporal_store(f32x4{Cr[0], Ci[0], Cr[1], Ci[1]}, dst);
            __builtin_nontemporal_store(f32x4{Cr[2], Ci[2], Cr[3], Ci[3]}, dst + 1);
        } else {
            __builtin_nontemporal_store(
                f32x4{Cr[0], Cr[1], Cr[2], Cr[3]},
                reinterpret_cast<f32x4*>(out + obase + (size_t)t * DIM));
        }
    }
}

// ---------------- fallback: proven 2-kernel chunked scan (round 3) ----------

__global__ __launch_bounds__(256, 2) void k1_carry(
    const float* __restrict__ x,
    const float* __restrict__ phr, const float* __restrict__ phi,
    const float* __restrict__ pir, const float* __restrict__ pii,
    float2* __restrict__ carry)
{
    const int d0 = threadIdx.x * VEC;
    const int c = blockIdx.x, b = blockIdx.y;

    float ar[VEC], ai[VEC], br[VEC], bi[VEC];
    load_params4(phr, phi, pir, pii, d0, ar, ai, br, bi);

    const float* xp = x + ((size_t)b * SEQ + (size_t)c * S2) * DIM + d0;
    float Cr[VEC] = {0.f, 0.f, 0.f, 0.f};
    float Ci[VEC] = {0.f, 0.f, 0.f, 0.f};
#pragma unroll 4
    for (int t = 0; t < S2; ++t) {
        float4 xv = *reinterpret_cast<const float4*>(xp + (size_t)t * DIM);
        float xa[VEC] = {xv.x, xv.y, xv.z, xv.w};
#pragma unroll
        for (int j = 0; j < VEC; ++j) {
            float nr = fmaf(ar[j], Cr[j], fmaf(-ai[j], Ci[j], br[j] * xa[j]));
            float ni = fmaf(ar[j], Ci[j], fmaf( ai[j], Cr[j], bi[j] * xa[j]));
            Cr[j] = nr; Ci[j] = ni;
        }
    }
    f32x4* cp = reinterpret_cast<f32x4*>(carry + ((size_t)b * NC2 + c) * DIM + d0);
    cp[0] = f32x4{Cr[0], Ci[0], Cr[1], Ci[1]};
    cp[1] = f32x4{Cr[2], Ci[2], Cr[3], Ci[3]};
}

template <bool CPLX>
__global__ __launch_bounds__(256, 2) void k2_out(
    const float* __restrict__ x,
    const float* __restrict__ phr, const float* __restrict__ phi,
    const float* __restrict__ pir, const float* __restrict__ pii,
    const float* __restrict__ hr,  const float* __restrict__ hi_,
    const float2* __restrict__ carry,
    float* __restrict__ out)
{
    const int d0 = threadIdx.x * VEC;
    const int c = blockIdx.x, b = blockIdx.y;

    float ar[VEC], ai[VEC], bqr[VEC], bqi[VEC];
    load_params4(phr, phi, pir, pii, d0, ar, ai, bqr, bqi);

    float ASr[VEC], ASi[VEC];
#pragma unroll
    for (int j = 0; j < VEC; ++j) {
        float sr = ar[j], si = ai[j];
#pragma unroll
        for (int k = 0; k < 5; ++k) {
            float nr = sr * sr - si * si;
            si = 2.f * sr * si;
            sr = nr;
        }
        ASr[j] = sr; ASi[j] = si;
    }

    float Pr[VEC] = {0.f, 0.f, 0.f, 0.f}, Pi[VEC] = {0.f, 0.f, 0.f, 0.f};
    float Mr[VEC] = {1.f, 1.f, 1.f, 1.f}, Mi[VEC] = {0.f, 0.f, 0.f, 0.f};
    const float2* cb = carry + (size_t)b * NC2 * DIM + d0;
#pragma unroll 4
    for (int k = c - 1; k >= 0; --k) {
        const f32x4* src = reinterpret_cast<const f32x4*>(cb + (size_t)k * DIM);
        f32x4 g0 = src[0], g1 = src[1];
        float gr[VEC] = {g0.x, g0.z, g1.x, g1.z};
        float gi[VEC] = {g0.y, g0.w, g1.y, g1.w};
#pragma unroll
        for (int j = 0; j < VEC; ++j) {
            Pr[j] = fmaf(Mr[j], gr[j], fmaf(-Mi[j], gi[j], Pr[j]));
            Pi[j] = fmaf(Mr[j], gi[j], fmaf( Mi[j], gr[j], Pi[j]));
            float nr = Mr[j] * ASr[j] - Mi[j] * ASi[j];
            Mi[j] = Mr[j] * ASi[j] + Mi[j] * ASr[j];
            Mr[j] = nr;
        }
    }
    {
        float4 hv_r = *reinterpret_cast<const float4*>(hr  + (size_t)b * DIM + d0);
        float4 hv_i = *reinterpret_cast<const float4*>(hi_ + (size_t)b * DIM + d0);
        float hrv[VEC] = {hv_r.x, hv_r.y, hv_r.z, hv_r.w};
        float hiv[VEC] = {hv_i.x, hv_i.y, hv_i.z, hv_i.w};
#pragma unroll
        for (int j = 0; j < VEC; ++j) {
            Pr[j] = fmaf(Mr[j], hrv[j], fmaf(-Mi[j], hiv[j], Pr[j]));
            Pi[j] = fmaf(Mr[j], hiv[j], fmaf( Mi[j], hrv[j], Pi[j]));
        }
    }

    float Cr[VEC], Ci[VEC];
#pragma unroll
    for (int j = 0; j < VEC; ++j) { Cr[j] = Pr[j]; Ci[j] = Pi[j]; }

    const float* xp = x + ((size_t)b * SEQ + (size_t)c * S2) * DIM + d0;
    const size_t obase = ((size_t)b * SEQ + (size_t)c * S2) * DIM + d0;
#pragma unroll 4
    for (int t = 0; t < S2; ++t) {
        float4 xv = *reinterpret_cast<const float4*>(xp + (size_t)t * DIM);
        float xa[VEC] = {xv.x, xv.y, xv.z, xv.w};
#pragma unroll
        for (int j = 0; j < VEC; ++j) {
            float nr = fmaf(ar[j], Cr[j], fmaf(-ai[j], Ci[j], bqr[j] * xa[j]));
            float ni = fmaf(ar[j], Ci[j], fmaf( ai[j], Cr[j], bqi[j] * xa[j]));
            Cr[j] = nr; Ci[j] = ni;
        }
        if (CPLX) {
            f32x4* dst = reinterpret_cast<f32x4*>(out + 2 * (obase + (size_t)t * DIM));
            __builtin_nontemporal_store(f32x4{Cr[0], Ci[0], Cr[1], Ci[1]}, dst);
            __builtin_nontemporal_store(f32x4{Cr[2], Ci[2], Cr[3], Ci[3]}, dst + 1);
        } else {
            __builtin_nontemporal_store(
                f32x4{Cr[0], Cr[1], Cr[2], Cr[3]},
                reinterpret_cast<f32x4*>(out + obase + (size_t)t * DIM));
        }
    }
}

// Scratch-free fallback: one thread per (b,d), serial scan over all of SEQ.
template <bool CPLX>
__global__ void k_serial(
    const float* __restrict__ x,
    const float* __restrict__ phr, const float* __restrict__ phi,
    const float* __restrict__ pir, const float* __restrict__ pii,
    const float* __restrict__ hr,  const float* __restrict__ hi_,
    float* __restrict__ out)
{
    const int idx = blockIdx.x * blockDim.x + threadIdx.x;  // b*DIM + d
    if (idx >= BATCH * DIM) return;
    const int b = idx / DIM, d = idx % DIM;

    float pr = phr[d], pi = phi[d];
    float mag = sqrtf(pr * pr + pi * pi);
    float sc = expf(-mag) / mag;
    float ar = pr * sc, ai = pi * sc;
    float br = pir[d], bi = pii[d];

    float Cr = hr[idx], Ci = hi_[idx];
    const float* xp = x + (size_t)b * SEQ * DIM + d;
    for (int t = 0; t < SEQ; ++t) {
        float xv = xp[(size_t)t * DIM];
        float nr = fmaf(ar, Cr, fmaf(-ai, Ci, br * xv));
        float ni = fmaf(ar, Ci, fmaf( ai, Cr, bi * xv));
        Cr = nr; Ci = ni;
        size_t o = ((size_t)b * SEQ + t) * DIM + d;
        if (CPLX) {
            reinterpret_cast<float2*>(out)[o] = make_float2(Cr, Ci);
        } else {
            out[o] = Cr;
        }
    }
}

template <bool CPLX>
static void dispatch(const float* x, const float* hr, const float* hi_,
                     const float* phr, const float* phi,
                     const float* pir, const float* pii,
                     float* out, void* d_ws, size_t ws_size, hipStream_t stream)
{
    // --- primary: cooperative single-kernel (needs 16 MiB ws) ---
    const size_t need_coop = (size_t)2 * BATCH * NCC * DIM * sizeof(float2);
    if (ws_size >= need_coop) {
        float2* carry  = (float2*)d_ws;
        float2* prefix = carry + (size_t)BATCH * NCC * DIM;
        void* args[] = {
            (void*)&x, (void*)&phr, (void*)&phi, (void*)&pir, (void*)&pii,
            (void*)&hr, (void*)&hi_, (void*)&carry, (void*)&prefix, (void*)&out
        };
        hipError_t e = hipLaunchCooperativeKernel(
            (const void*)&k_coop<CPLX>, dim3(BATCH * NCC), dim3(256),
            args, 0, stream);
        if (e == hipSuccess) return;
        // fall through to non-cooperative path on launch failure
    }

    // --- fallback: proven 2-kernel chunked scan ---
    const size_t need2 = (size_t)BATCH * NC2 * DIM * sizeof(float2);  // 4 MiB
    if (ws_size >= need2) {
        float2* carry = (float2*)d_ws;
        dim3 blk(256);
        dim3 g(NC2, BATCH);
        k1_carry<<<g, blk, 0, stream>>>(x, phr, phi, pir, pii, carry);
        k2_out<CPLX><<<g, blk, 0, stream>>>(
            x, phr, phi, pir, pii, hr, hi_, carry, out);
    } else {
        k_serial<CPLX><<<dim3((BATCH * DIM + 255) / 256), dim3(256), 0, stream>>>(
            x, phr, phi, pir, pii, hr, hi_, out);
    }
}

extern "C" void kernel_launch(void* const* d_in, const int* in_sizes, int n_in,
                              void* d_out, int out_size, void* d_ws, size_t ws_size,
                              hipStream_t stream) {
    const float* x   = (const float*)d_in[0];
    const float* hr  = (const float*)d_in[1];
    const float* hi_ = (const float*)d_in[2];
    const float* phr = (const float*)d_in[3];
    const float* phi = (const float*)d_in[4];
    const float* pir = (const float*)d_in[5];
    const float* pii = (const float*)d_in[6];
    float* out = (float*)d_out;

    const size_t total = (size_t)BATCH * SEQ * DIM;
    // out_size >= 2*total  -> buffer holds interleaved complex64 (re,im pairs)
    // otherwise            -> buffer holds exactly total floats: write real part
    if ((size_t)out_size >= 2 * total)
        dispatch<true >(x, hr, hi_, phr, phi, pir, pii, out, d_ws, ws_size, stream);
    else
        dispatch<false>(x, hr, hi_, phr, phi, pir, pii, out, d_ws, ws_size, stream);
}

// Round 5
// 196.946 us; speedup vs baseline: 3.3519x; 3.3519x over previous
//
#include <hip/hip_runtime.h>
#include <math.h>

#define BATCH 4
#define SEQ   4096
#define DIM   1024
#define VEC   4

// 2-kernel chunked scan: NCC chunks of SCC rows.
#define NCC 256
#define SCC (SEQ / NCC)   // 16

typedef float f32x4 __attribute__((ext_vector_type(4)));

// Per-d parameters: a = phazor = p/|p| * exp(-|p|), b = phazor_init.
__device__ __forceinline__ void load_params4(
    const float* __restrict__ phr, const float* __restrict__ phi,
    const float* __restrict__ pir, const float* __restrict__ pii,
    int d0, float* ar, float* ai, float* br, float* bi)
{
    float4 p_r = *reinterpret_cast<const float4*>(phr + d0);
    float4 p_i = *reinterpret_cast<const float4*>(phi + d0);
    float4 q_r = *reinterpret_cast<const float4*>(pir + d0);
    float4 q_i = *reinterpret_cast<const float4*>(pii + d0);
    float prv[VEC] = {p_r.x, p_r.y, p_r.z, p_r.w};
    float piv[VEC] = {p_i.x, p_i.y, p_i.z, p_i.w};
    float qrv[VEC] = {q_r.x, q_r.y, q_r.z, q_r.w};
    float qiv[VEC] = {q_i.x, q_i.y, q_i.z, q_i.w};
#pragma unroll
    for (int j = 0; j < VEC; ++j) {
        float mag = sqrtf(prv[j] * prv[j] + piv[j] * piv[j]);
        float s = expf(-mag) / mag;
        ar[j] = prv[j] * s;
        ai[j] = piv[j] * s;
        br[j] = qrv[j];
        bi[j] = qiv[j];
    }
}

// K1: per-chunk local scan with zero initial state -> chunk carries.
// Grid (NCC, BATCH) = 1024 blocks of 256 threads; (256,4) -> <=128 VGPR,
// 4 blocks/CU, 16 waves/CU.
__global__ __launch_bounds__(256, 4) void k1_carry(
    const float* __restrict__ x,
    const float* __restrict__ phr, const float* __restrict__ phi,
    const float* __restrict__ pir, const float* __restrict__ pii,
    float2* __restrict__ carry)
{
    const int d0 = threadIdx.x * VEC;
    const int c = blockIdx.x, b = blockIdx.y;

    float ar[VEC], ai[VEC], br[VEC], bi[VEC];
    load_params4(phr, phi, pir, pii, d0, ar, ai, br, bi);

    const float* xp = x + ((size_t)b * SEQ + (size_t)c * SCC) * DIM + d0;
    float Cr[VEC] = {0.f, 0.f, 0.f, 0.f};
    float Ci[VEC] = {0.f, 0.f, 0.f, 0.f};
#pragma unroll 4
    for (int t = 0; t < SCC; ++t) {
        float4 xv = *reinterpret_cast<const float4*>(xp + (size_t)t * DIM);
        float xa[VEC] = {xv.x, xv.y, xv.z, xv.w};
#pragma unroll
        for (int j = 0; j < VEC; ++j) {
            float nr = fmaf(ar[j], Cr[j], fmaf(-ai[j], Ci[j], br[j] * xa[j]));
            float ni = fmaf(ar[j], Ci[j], fmaf( ai[j], Cr[j], bi[j] * xa[j]));
            Cr[j] = nr; Ci[j] = ni;
        }
    }
    f32x4* cp = reinterpret_cast<f32x4*>(carry + ((size_t)b * NCC + c) * DIM + d0);
    cp[0] = f32x4{Cr[0], Ci[0], Cr[1], Ci[1]};
    cp[1] = f32x4{Cr[2], Ci[2], Cr[3], Ci[3]};
}

// K2: block computes its own seed redundantly from the carries (independent
// L2 loads + a register power chain M *= A^SCC), then runs the seeded output
// scan over its x chunk. Chunk index is PERMUTED across blockIdx so each CU
// hosts a mix of short (small c) and long (large c) seed loops -- this is
// what killed round-3's occupancy (9.8%): consecutive same-CU blocks had
// monotonically growing seed cost. NT stores for out (never re-read).
template <bool CPLX>
__global__ __launch_bounds__(256, 4) void k2_out(
    const float* __restrict__ x,
    const float* __restrict__ phr, const float* __restrict__ phi,
    const float* __restrict__ pir, const float* __restrict__ pii,
    const float* __restrict__ hr,  const float* __restrict__ hi_,
    const float2* __restrict__ carry,
    float* __restrict__ out)
{
    const int d0 = threadIdx.x * VEC;
    const int bx = blockIdx.x, b = blockIdx.y;
    // bijective spread: consecutive bx differ by 32 in c
    const int c = ((bx & 7) << 5) | (bx >> 3);

    float ar[VEC], ai[VEC], bqr[VEC], bqi[VEC];
    load_params4(phr, phi, pir, pii, d0, ar, ai, bqr, bqi);

    // A_S = a^SCC (SCC=16 -> 4 squarings)
    float ASr[VEC], ASi[VEC];
#pragma unroll
    for (int j = 0; j < VEC; ++j) {
        float sr = ar[j], si = ai[j];
#pragma unroll
        for (int k = 0; k < 4; ++k) {
            float nr = sr * sr - si * si;
            si = 2.f * sr * si;
            sr = nr;
        }
        ASr[j] = sr; ASi[j] = si;
    }

    // Seed: P = sum_{k<c} A_S^{c-1-k} * carry_k + A_S^c * h
    float Pr[VEC] = {0.f, 0.f, 0.f, 0.f}, Pi[VEC] = {0.f, 0.f, 0.f, 0.f};
    float Mr[VEC] = {1.f, 1.f, 1.f, 1.f}, Mi[VEC] = {0.f, 0.f, 0.f, 0.f};
    const float2* cb = carry + (size_t)b * NCC * DIM + d0;
#pragma unroll 4
    for (int k = c - 1; k >= 0; --k) {
        const f32x4* src = reinterpret_cast<const f32x4*>(cb + (size_t)k * DIM);
        f32x4 g0 = src[0], g1 = src[1];
        float gr[VEC] = {g0.x, g0.z, g1.x, g1.z};
        float gi[VEC] = {g0.y, g0.w, g1.y, g1.w};
#pragma unroll
        for (int j = 0; j < VEC; ++j) {
            Pr[j] = fmaf(Mr[j], gr[j], fmaf(-Mi[j], gi[j], Pr[j]));
            Pi[j] = fmaf(Mr[j], gi[j], fmaf( Mi[j], gr[j], Pi[j]));
            float nr = Mr[j] * ASr[j] - Mi[j] * ASi[j];
            Mi[j] = Mr[j] * ASi[j] + Mi[j] * ASr[j];
            Mr[j] = nr;
        }
    }
    {
        float4 hv_r = *reinterpret_cast<const float4*>(hr  + (size_t)b * DIM + d0);
        float4 hv_i = *reinterpret_cast<const float4*>(hi_ + (size_t)b * DIM + d0);
        float hrv[VEC] = {hv_r.x, hv_r.y, hv_r.z, hv_r.w};
        float hiv[VEC] = {hv_i.x, hv_i.y, hv_i.z, hv_i.w};
#pragma unroll
        for (int j = 0; j < VEC; ++j) {
            Pr[j] = fmaf(Mr[j], hrv[j], fmaf(-Mi[j], hiv[j], Pr[j]));
            Pi[j] = fmaf(Mr[j], hiv[j], fmaf( Mi[j], hrv[j], Pi[j]));
        }
    }

    // Seeded output scan over this chunk.
    float Cr[VEC], Ci[VEC];
#pragma unroll
    for (int j = 0; j < VEC; ++j) { Cr[j] = Pr[j]; Ci[j] = Pi[j]; }

    const float* xp = x + ((size_t)b * SEQ + (size_t)c * SCC) * DIM + d0;
    const size_t obase = ((size_t)b * SEQ + (size_t)c * SCC) * DIM + d0;
#pragma unroll 4
    for (int t = 0; t < SCC; ++t) {
        float4 xv = *reinterpret_cast<const float4*>(xp + (size_t)t * DIM);
        float xa[VEC] = {xv.x, xv.y, xv.z, xv.w};
#pragma unroll
        for (int j = 0; j < VEC; ++j) {
            float nr = fmaf(ar[j], Cr[j], fmaf(-ai[j], Ci[j], bqr[j] * xa[j]));
            float ni = fmaf(ar[j], Ci[j], fmaf( ai[j], Cr[j], bqi[j] * xa[j]));
            Cr[j] = nr; Ci[j] = ni;
        }
        if (CPLX) {
            f32x4* dst = reinterpret_cast<f32x4*>(out + 2 * (obase + (size_t)t * DIM));
            __builtin_nontemporal_store(f32x4{Cr[0], Ci[0], Cr[1], Ci[1]}, dst);
            __builtin_nontemporal_store(f32x4{Cr[2], Ci[2], Cr[3], Ci[3]}, dst + 1);
        } else {
            __builtin_nontemporal_store(
                f32x4{Cr[0], Cr[1], Cr[2], Cr[3]},
                reinterpret_cast<f32x4*>(out + obase + (size_t)t * DIM));
        }
    }
}

// Scratch-free fallback: one thread per (b,d), serial scan over all of SEQ.
template <bool CPLX>
__global__ void k_serial(
    const float* __restrict__ x,
    const float* __restrict__ phr, const float* __restrict__ phi,
    const float* __restrict__ pir, const float* __restrict__ pii,
    const float* __restrict__ hr,  const float* __restrict__ hi_,
    float* __restrict__ out)
{
    const int idx = blockIdx.x * blockDim.x + threadIdx.x;  // b*DIM + d
    if (idx >= BATCH * DIM) return;
    const int b = idx / DIM, d = idx % DIM;

    float pr = phr[d], pi = phi[d];
    float mag = sqrtf(pr * pr + pi * pi);
    float sc = expf(-mag) / mag;
    float ar = pr * sc, ai = pi * sc;
    float br = pir[d], bi = pii[d];

    float Cr = hr[idx], Ci = hi_[idx];
    const float* xp = x + (size_t)b * SEQ * DIM + d;
    for (int t = 0; t < SEQ; ++t) {
        float xv = xp[(size_t)t * DIM];
        float nr = fmaf(ar, Cr, fmaf(-ai, Ci, br * xv));
        float ni = fmaf(ar, Ci, fmaf( ai, Cr, bi * xv));
        Cr = nr; Ci = ni;
        size_t o = ((size_t)b * SEQ + t) * DIM + d;
        if (CPLX) {
            reinterpret_cast<float2*>(out)[o] = make_float2(Cr, Ci);
        } else {
            out[o] = Cr;
        }
    }
}

template <bool CPLX>
static void dispatch(const float* x, const float* hr, const float* hi_,
                     const float* phr, const float* phi,
                     const float* pir, const float* pii,
                     float* out, void* d_ws, size_t ws_size, hipStream_t stream)
{
    const size_t need = (size_t)BATCH * NCC * DIM * sizeof(float2);  // 8 MiB
    if (ws_size >= need) {
        float2* carry = (float2*)d_ws;
        dim3 blk(256);
        dim3 g(NCC, BATCH);
        k1_carry<<<g, blk, 0, stream>>>(x, phr, phi, pir, pii, carry);
        k2_out<CPLX><<<g, blk, 0, stream>>>(
            x, phr, phi, pir, pii, hr, hi_, carry, out);
    } else {
        k_serial<CPLX><<<dim3((BATCH * DIM + 255) / 256), dim3(256), 0, stream>>>(
            x, phr, phi, pir, pii, hr, hi_, out);
    }
}

extern "C" void kernel_launch(void* const* d_in, const int* in_sizes, int n_in,
                              void* d_out, int out_size, void* d_ws, size_t ws_size,
                              hipStream_t stream) {
    const float* x   = (const float*)d_in[0];
    const float* hr  = (const float*)d_in[1];
    const float* hi_ = (const float*)d_in[2];
    const float* phr = (const float*)d_in[3];
    const float* phi = (const float*)d_in[4];
    const float* pir = (const float*)d_in[5];
    const float* pii = (const float*)d_in[6];
    float* out = (float*)d_out;

    const size_t total = (size_t)BATCH * SEQ * DIM;
    // out_size >= 2*total  -> buffer holds interleaved complex64 (re,im pairs)
    // otherwise            -> buffer holds exactly total floats: write real part
    if ((size_t)out_size >= 2 * total)
        dispatch<true >(x, hr, hi_, phr, phi, pir, pii, out, d_ws, ws_size, stream);
    else
        dispatch<false>(x, hr, hi_, phr, phi, pir, pii, out, d_ws, ws_size, stream);
}

// Round 6
// 147.721 us; speedup vs baseline: 4.4689x; 1.3332x over previous
//
#include <hip/hip_runtime.h>
#include <math.h>

#define BATCH 4
#define SEQ   4096
#define DIM   1024
#define VEC   4

// 3-kernel chunked scan: NCC chunks of SCC rows; exact fine-grained prefix.
#define NCC 256
#define SCC (SEQ / NCC)   // 16

typedef float f32x4 __attribute__((ext_vector_type(4)));

// Per-d parameters: a = phazor = p/|p| * exp(-|p|), b = phazor_init.
__device__ __forceinline__ void load_params4(
    const float* __restrict__ phr, const float* __restrict__ phi,
    const float* __restrict__ pir, const float* __restrict__ pii,
    int d0, float* ar, float* ai, float* br, float* bi)
{
    float4 p_r = *reinterpret_cast<const float4*>(phr + d0);
    float4 p_i = *reinterpret_cast<const float4*>(phi + d0);
    float4 q_r = *reinterpret_cast<const float4*>(pir + d0);
    float4 q_i = *reinterpret_cast<const float4*>(pii + d0);
    float prv[VEC] = {p_r.x, p_r.y, p_r.z, p_r.w};
    float piv[VEC] = {p_i.x, p_i.y, p_i.z, p_i.w};
    float qrv[VEC] = {q_r.x, q_r.y, q_r.z, q_r.w};
    float qiv[VEC] = {q_i.x, q_i.y, q_i.z, q_i.w};
#pragma unroll
    for (int j = 0; j < VEC; ++j) {
        float mag = sqrtf(prv[j] * prv[j] + piv[j] * piv[j]);
        float s = expf(-mag) / mag;
        ar[j] = prv[j] * s;
        ai[j] = piv[j] * s;
        br[j] = qrv[j];
        bi[j] = qiv[j];
    }
}

// K1: per-chunk local scan with zero initial state -> chunk carries.
// Grid (NCC, BATCH) = 1024 blocks of 256 threads; (256,4) -> 4 blocks/CU.
__global__ __launch_bounds__(256, 4) void k1_carry(
    const float* __restrict__ x,
    const float* __restrict__ phr, const float* __restrict__ phi,
    const float* __restrict__ pir, const float* __restrict__ pii,
    float2* __restrict__ carry)
{
    const int d0 = threadIdx.x * VEC;
    const int c = blockIdx.x, b = blockIdx.y;

    float ar[VEC], ai[VEC], br[VEC], bi[VEC];
    load_params4(phr, phi, pir, pii, d0, ar, ai, br, bi);

    const float* xp = x + ((size_t)b * SEQ + (size_t)c * SCC) * DIM + d0;
    float Cr[VEC] = {0.f, 0.f, 0.f, 0.f};
    float Ci[VEC] = {0.f, 0.f, 0.f, 0.f};
#pragma unroll 4
    for (int t = 0; t < SCC; ++t) {
        float4 xv = *reinterpret_cast<const float4*>(xp + (size_t)t * DIM);
        float xa[VEC] = {xv.x, xv.y, xv.z, xv.w};
#pragma unroll
        for (int j = 0; j < VEC; ++j) {
            float nr = fmaf(ar[j], Cr[j], fmaf(-ai[j], Ci[j], br[j] * xa[j]));
            float ni = fmaf(ar[j], Ci[j], fmaf( ai[j], Cr[j], bi[j] * xa[j]));
            Cr[j] = nr; Ci[j] = ni;
        }
    }
    f32x4* cp = reinterpret_cast<f32x4*>(carry + ((size_t)b * NCC + c) * DIM + d0);
    cp[0] = f32x4{Cr[0], Ci[0], Cr[1], Ci[1]};
    cp[1] = f32x4{Cr[2], Ci[2], Cr[3], Ci[3]};
}

// K2: exact per-(b,d) prefix over the NCC carries, seeded with hidden.
// 4096 threads = 64 blocks x 64 (1 wave/CU on 64 CUs). Carry loads batched
// TILE=8 (independent within a tile -> one L2 roundtrip per tile, not per k).
__global__ __launch_bounds__(64) void k_prefix(
    const float* __restrict__ phr, const float* __restrict__ phi,
    const float* __restrict__ hr,  const float* __restrict__ hi_,
    const float2* __restrict__ carry,
    float2* __restrict__ prefix)
{
    const int idx = blockIdx.x * 64 + threadIdx.x;  // b*DIM + d
    const int b = idx >> 10, d = idx & (DIM - 1);

    float pr = phr[d], pi = phi[d];
    float mag = sqrtf(pr * pr + pi * pi);
    float sc = expf(-mag) / mag;
    float a1r = pr * sc, a1i = pi * sc;

    // AS = a^SCC (SCC=16 -> 4 squarings)
    float ASr = a1r, ASi = a1i;
#pragma unroll
    for (int k = 0; k < 4; ++k) {
        float nr = ASr * ASr - ASi * ASi;
        ASi = 2.f * ASr * ASi;
        ASr = nr;
    }

    float Pr = hr[idx], Pi = hi_[idx];
    const float2* cb = carry  + (size_t)b * NCC * DIM + d;
    float2*       pp = prefix + (size_t)b * NCC * DIM + d;
    constexpr int TILE = 8;
    for (int base = 0; base < NCC; base += TILE) {
        float2 cv[TILE];
#pragma unroll
        for (int k = 0; k < TILE; ++k)
            cv[k] = cb[(size_t)(base + k) * DIM];
#pragma unroll
        for (int k = 0; k < TILE; ++k) {
            pp[(size_t)(base + k) * DIM] = make_float2(Pr, Pi);
            float nr = fmaf(ASr, Pr, fmaf(-ASi, Pi, cv[k].x));
            float ni = fmaf(ASr, Pi, fmaf( ASi, Pr, cv[k].y));
            Pr = nr; Pi = ni;
        }
    }
}

// K3: seed from prefix (no per-block seed recompute -- that was R5's O(NC^2)
// mistake), stream x (L3-hot after K1), NT-store out.
template <bool CPLX>
__global__ __launch_bounds__(256, 4) void k_out(
    const float* __restrict__ x,
    const float* __restrict__ phr, const float* __restrict__ phi,
    const float* __restrict__ pir, const float* __restrict__ pii,
    const float2* __restrict__ prefix,
    float* __restrict__ out)
{
    const int d0 = threadIdx.x * VEC;
    const int c = blockIdx.x, b = blockIdx.y;

    // issue seed load first (longest-latency independent load)
    const f32x4* sp =
        reinterpret_cast<const f32x4*>(prefix + ((size_t)b * NCC + c) * DIM + d0);
    f32x4 s0 = sp[0], s1 = sp[1];

    float ar[VEC], ai[VEC], bqr[VEC], bqi[VEC];
    load_params4(phr, phi, pir, pii, d0, ar, ai, bqr, bqi);

    float Cr[VEC], Ci[VEC];
    Cr[0] = s0.x; Ci[0] = s0.y; Cr[1] = s0.z; Ci[1] = s0.w;
    Cr[2] = s1.x; Ci[2] = s1.y; Cr[3] = s1.z; Ci[3] = s1.w;

    const float* xp = x + ((size_t)b * SEQ + (size_t)c * SCC) * DIM + d0;
    const size_t obase = ((size_t)b * SEQ + (size_t)c * SCC) * DIM + d0;
#pragma unroll 4
    for (int t = 0; t < SCC; ++t) {
        float4 xv = *reinterpret_cast<const float4*>(xp + (size_t)t * DIM);
        float xa[VEC] = {xv.x, xv.y, xv.z, xv.w};
#pragma unroll
        for (int j = 0; j < VEC; ++j) {
            float nr = fmaf(ar[j], Cr[j], fmaf(-ai[j], Ci[j], bqr[j] * xa[j]));
            float ni = fmaf(ar[j], Ci[j], fmaf( ai[j], Cr[j], bqi[j] * xa[j]));
            Cr[j] = nr; Ci[j] = ni;
        }
        if (CPLX) {
            f32x4* dst = reinterpret_cast<f32x4*>(out + 2 * (obase + (size_t)t * DIM));
            __builtin_nontemporal_store(f32x4{Cr[0], Ci[0], Cr[1], Ci[1]}, dst);
            __builtin_nontemporal_store(f32x4{Cr[2], Ci[2], Cr[3], Ci[3]}, dst + 1);
        } else {
            __builtin_nontemporal_store(
                f32x4{Cr[0], Cr[1], Cr[2], Cr[3]},
                reinterpret_cast<f32x4*>(out + obase + (size_t)t * DIM));
        }
    }
}

// Scratch-free fallback: one thread per (b,d), serial scan over all of SEQ.
template <bool CPLX>
__global__ void k_serial(
    const float* __restrict__ x,
    const float* __restrict__ phr, const float* __restrict__ phi,
    const float* __restrict__ pir, const float* __restrict__ pii,
    const float* __restrict__ hr,  const float* __restrict__ hi_,
    float* __restrict__ out)
{
    const int idx = blockIdx.x * blockDim.x + threadIdx.x;  // b*DIM + d
    if (idx >= BATCH * DIM) return;
    const int b = idx / DIM, d = idx % DIM;

    float pr = phr[d], pi = phi[d];
    float mag = sqrtf(pr * pr + pi * pi);
    float sc = expf(-mag) / mag;
    float ar = pr * sc, ai = pi * sc;
    float br = pir[d], bi = pii[d];

    float Cr = hr[idx], Ci = hi_[idx];
    const float* xp = x + (size_t)b * SEQ * DIM + d;
    for (int t = 0; t < SEQ; ++t) {
        float xv = xp[(size_t)t * DIM];
        float nr = fmaf(ar, Cr, fmaf(-ai, Ci, br * xv));
        float ni = fmaf(ar, Ci, fmaf( ai, Cr, bi * xv));
        Cr = nr; Ci = ni;
        size_t o = ((size_t)b * SEQ + t) * DIM + d;
        if (CPLX) {
            reinterpret_cast<float2*>(out)[o] = make_float2(Cr, Ci);
        } else {
            out[o] = Cr;
        }
    }
}

template <bool CPLX>
static void dispatch(const float* x, const float* hr, const float* hi_,
                     const float* phr, const float* phi,
                     const float* pir, const float* pii,
                     float* out, void* d_ws, size_t ws_size, hipStream_t stream)
{
    // ws: carries (8 MiB) + prefixes (8 MiB)
    const size_t need = (size_t)2 * BATCH * NCC * DIM * sizeof(float2);
    if (ws_size >= need) {
        float2* carry  = (float2*)d_ws;
        float2* prefix = carry + (size_t)BATCH * NCC * DIM;
        dim3 blk(256);
        dim3 g(NCC, BATCH);
        k1_carry<<<g, blk, 0, stream>>>(x, phr, phi, pir, pii, carry);
        k_prefix<<<dim3(BATCH * DIM / 64), dim3(64), 0, stream>>>(
            phr, phi, hr, hi_, carry, prefix);
        k_out<CPLX><<<g, blk, 0, stream>>>(
            x, phr, phi, pir, pii, prefix, out);
    } else {
        k_serial<CPLX><<<dim3((BATCH * DIM + 255) / 256), dim3(256), 0, stream>>>(
            x, phr, phi, pir, pii, hr, hi_, out);
    }
}

extern "C" void kernel_launch(void* const* d_in, const int* in_sizes, int n_in,
                              void* d_out, int out_size, void* d_ws, size_t ws_size,
                              hipStream_t stream) {
    const float* x   = (const float*)d_in[0];
    const float* hr  = (const float*)d_in[1];
    const float* hi_ = (const float*)d_in[2];
    const float* phr = (const float*)d_in[3];
    const float* phi = (const float*)d_in[4];
    const float* pir = (const float*)d_in[5];
    const float* pii = (const float*)d_in[6];
    float* out = (float*)d_out;

    const size_t total = (size_t)BATCH * SEQ * DIM;
    // out_size >= 2*total  -> buffer holds interleaved complex64 (re,im pairs)
    // otherwise            -> buffer holds exactly total floats: write real part
    if ((size_t)out_size >= 2 * total)
        dispatch<true >(x, hr, hi_, phr, phi, pir, pii, out, d_ws, ws_size, stream);
    else
        dispatch<false>(x, hr, hi_, phr, phi, pir, pii, out, d_ws, ws_size, stream);
}